// Round 1
// baseline (1225.769 us; speedup 1.0000x reference)
//
#include <hip/hip_runtime.h>
#include <math.h>

#define NB  64
#define TT  1024
#define H2  512      // 2*H
#define HH  256      // H
#define SS  128      // style dim
#define OO  80
#define G3  1536     // 3*2H
#define FIN_A 896    // 3H+S (ga_ih inner dim)
#define FIN_1 1152   // 4H+S (wsc / g1_ih inner dim)

__device__ __forceinline__ float sigmoidf(float x) { return 1.0f / (1.0f + expf(-x)); }

// t1 = relu(input_dec @ pw1.T + pb1)   (64,512)
__global__ void k_l1(const float* __restrict__ xdec, const float* __restrict__ pw1,
                     const float* __restrict__ pb1, float* __restrict__ t1) {
    int tid = blockIdx.x * blockDim.x + threadIdx.x;   // n*512 + i
    int n = tid >> 9, i = tid & 511;
    float acc = pb1[i];
    const float* x = xdec + n * OO;
    const float* w = pw1 + i * OO;
    #pragma unroll 8
    for (int k = 0; k < OO; ++k) acc += x[k] * w[k];
    t1[tid] = fmaxf(acc, 0.0f);
}

// pre = relu(t1 @ pw2.T + pb2)   (64,256)
__global__ void k_l2(const float* __restrict__ t1, const float* __restrict__ pw2,
                     const float* __restrict__ pb2, float* __restrict__ pre) {
    int tid = blockIdx.x * blockDim.x + threadIdx.x;   // n*256 + i
    int n = tid >> 8, i = tid & 255;
    float acc = pb2[i];
    const float* x = t1 + n * H2;
    const float* w = pw2 + i * H2;
    #pragma unroll 8
    for (int k = 0; k < H2; ++k) acc += x[k] * w[k];
    pre[tid] = fmaxf(acc, 0.0f);
}

// out_att = GRU(x_att, h=0): x_att = [pre(256), zeros(512), sv(128)]; gh = b_hh only.
__global__ void k_gruA(const float* __restrict__ pre, const float* __restrict__ sv,
                       const float* __restrict__ ga_ih, const float* __restrict__ ga_bih,
                       const float* __restrict__ ga_bhh, float* __restrict__ out_att) {
    int tid = blockIdx.x * blockDim.x + threadIdx.x;   // n*512 + j
    int n = tid >> 9, j = tid & 511;
    float gr = ga_bih[j], gz = ga_bih[H2 + j], gn = ga_bih[2 * H2 + j];
    const float* wr = ga_ih + (size_t)j * FIN_A;
    const float* wz = ga_ih + (size_t)(H2 + j) * FIN_A;
    const float* wn = ga_ih + (size_t)(2 * H2 + j) * FIN_A;
    const float* xp = pre + n * HH;
    #pragma unroll 8
    for (int k = 0; k < HH; ++k) {
        float x = xp[k];
        gr += x * wr[k]; gz += x * wz[k]; gn += x * wn[k];
    }
    const float* xs = sv + n * SS;
    #pragma unroll 8
    for (int k = 0; k < SS; ++k) {
        float x = xs[k];
        gr += x * wr[768 + k]; gz += x * wz[768 + k]; gn += x * wn[768 + k];
    }
    float r = sigmoidf(gr + ga_bhh[j]);
    float z = sigmoidf(gz + ga_bhh[H2 + j]);
    float nn = tanhf(gn + r * ga_bhh[2 * H2 + j]);
    out_att[tid] = (1.0f - z) * nn;
}

// attW_dec = out_att @ wdec.T + bdec   (64,512)
__global__ void k_attw(const float* __restrict__ out_att, const float* __restrict__ wdec,
                       const float* __restrict__ bdec, float* __restrict__ attW_dec) {
    int tid = blockIdx.x * blockDim.x + threadIdx.x;
    int n = tid >> 9, i = tid & 511;
    float acc = bdec[i];
    const float* x = out_att + n * H2;
    const float* w = wdec + (size_t)i * H2;
    #pragma unroll 8
    for (int k = 0; k < H2; ++k) acc += x[k] * w[k];
    attW_dec[tid] = acc;
}

// score pass: one wave per (n,t) row.  ew[n,t] = mask * exp(sum_d tanh(enc+dec)*wattn + battn)
__global__ void k_score(const float* __restrict__ attw_enc, const float* __restrict__ attW_dec,
                        const float* __restrict__ wattn, const float* __restrict__ battn,
                        const int* __restrict__ lengths,
                        float* __restrict__ ew, float* __restrict__ den) {
    int wave = threadIdx.x >> 6, lane = threadIdx.x & 63;
    int row = blockIdx.x * 4 + wave;                 // n*1024 + t
    int n = row >> 10, t = row & 1023;
    const float4* e4 = (const float4*)(attw_enc + (size_t)row * H2);
    const float4* d4 = (const float4*)(attW_dec + n * H2);
    const float4* w4 = (const float4*)wattn;
    float partial = 0.0f;
    #pragma unroll
    for (int p = 0; p < 2; ++p) {
        int idx = lane + p * 64;
        float4 e = e4[idx], d = d4[idx], w = w4[idx];
        partial += tanhf(e.x + d.x) * w.x + tanhf(e.y + d.y) * w.y +
                   tanhf(e.z + d.z) * w.z + tanhf(e.w + d.w) * w.w;
    }
    #pragma unroll
    for (int off = 32; off > 0; off >>= 1) partial += __shfl_xor(partial, off, 64);
    if (lane == 0) {
        float v = (t < lengths[n]) ? expf(partial + battn[0]) : 0.0f;
        ew[row] = v;
        atomicAdd(&den[n], v);
    }
}

// weighted sum: num[n,d] += sum_t ew[n,t] * enc[n,t,d]   (grid: 16 t-chunks x 64 n)
__global__ void k_apply(const float* __restrict__ enc, const float* __restrict__ ew,
                        float* __restrict__ num) {
    int n = blockIdx.y;
    int t0 = blockIdx.x * 64;
    int tid = threadIdx.x;
    const float2* e2 = (const float2*)(enc + ((size_t)n * TT + t0) * H2);
    const float* ewn = ew + n * TT + t0;
    float ax = 0.0f, ay = 0.0f;
    for (int t = 0; t < 64; ++t) {
        float w = ewn[t];
        float2 v = e2[(size_t)t * 256 + tid];
        ax += w * v.x; ay += w * v.y;
    }
    atomicAdd(&num[n * H2 + 2 * tid], ax);
    atomicAdd(&num[n * H2 + 2 * tid + 1], ay);
}

// attn_applied = num/den -> out[10240..] and out_dec = [attn, out_att, sv]
__global__ void k_finalize(const float* __restrict__ num, const float* __restrict__ den,
                           const float* __restrict__ out_att, const float* __restrict__ sv,
                           float* __restrict__ out, float* __restrict__ out_dec) {
    int tid = blockIdx.x * blockDim.x + threadIdx.x;   // n*512 + d
    int n = tid >> 9, d = tid & 511;
    float denom = fmaxf(den[n], 1e-12f);
    float a = num[tid] / denom;
    out[NB * 160 + tid] = a;                // second output chunk (attn_applied)
    float* od = out_dec + (size_t)n * FIN_1;
    od[d] = a;
    od[H2 + d] = out_att[tid];
    if (d < SS) od[2 * H2 + d] = sv[n * SS + d];
}

// residual1 = out_dec @ wsc.T + bsc + GRU1(out_dec, 0)
__global__ void k_sc_h1(const float* __restrict__ out_dec, const float* __restrict__ wsc,
                        const float* __restrict__ bsc, const float* __restrict__ g1_ih,
                        const float* __restrict__ g1_bih, const float* __restrict__ g1_bhh,
                        float* __restrict__ res1) {
    int tid = blockIdx.x * blockDim.x + threadIdx.x;   // n*512 + j
    int n = tid >> 9, j = tid & 511;
    float sc = bsc[j];
    float gr = g1_bih[j], gz = g1_bih[H2 + j], gn = g1_bih[2 * H2 + j];
    const float* ws_ = wsc + (size_t)j * FIN_1;
    const float* wr = g1_ih + (size_t)j * FIN_1;
    const float* wz = g1_ih + (size_t)(H2 + j) * FIN_1;
    const float* wn = g1_ih + (size_t)(2 * H2 + j) * FIN_1;
    const float* x = out_dec + (size_t)n * FIN_1;
    #pragma unroll 4
    for (int k = 0; k < FIN_1; ++k) {
        float xv = x[k];
        sc += xv * ws_[k]; gr += xv * wr[k]; gz += xv * wz[k]; gn += xv * wn[k];
    }
    float r = sigmoidf(gr + g1_bhh[j]);
    float z = sigmoidf(gz + g1_bhh[H2 + j]);
    float nn = tanhf(gn + r * g1_bhh[2 * H2 + j]);
    res1[tid] = sc + (1.0f - z) * nn;
}

// residual2 = residual1 + GRU2(residual1, 0)
__global__ void k_h2(const float* __restrict__ res1, const float* __restrict__ g2_ih,
                     const float* __restrict__ g2_bih, const float* __restrict__ g2_bhh,
                     float* __restrict__ res2) {
    int tid = blockIdx.x * blockDim.x + threadIdx.x;
    int n = tid >> 9, j = tid & 511;
    float gr = g2_bih[j], gz = g2_bih[H2 + j], gn = g2_bih[2 * H2 + j];
    const float* wr = g2_ih + (size_t)j * H2;
    const float* wz = g2_ih + (size_t)(H2 + j) * H2;
    const float* wn = g2_ih + (size_t)(2 * H2 + j) * H2;
    const float* x = res1 + n * H2;
    #pragma unroll 8
    for (int k = 0; k < H2; ++k) {
        float xv = x[k];
        gr += xv * wr[k]; gz += xv * wz[k]; gn += xv * wn[k];
    }
    float r = sigmoidf(gr + g2_bhh[j]);
    float z = sigmoidf(gz + g2_bhh[H2 + j]);
    float nn = tanhf(gn + r * g2_bhh[2 * H2 + j]);
    res2[tid] = res1[tid] + (1.0f - z) * nn;
}

// output = res2 @ wout.T + bout  -> out[0 .. 10240)
__global__ void k_out(const float* __restrict__ res2, const float* __restrict__ wout,
                      const float* __restrict__ bout, float* __restrict__ out) {
    int tid = blockIdx.x * blockDim.x + threadIdx.x;   // n*160 + i
    if (tid >= NB * 160) return;
    int n = tid / 160, i = tid % 160;
    float acc = bout[i];
    const float* x = res2 + n * H2;
    const float* w = wout + (size_t)i * H2;
    #pragma unroll 8
    for (int k = 0; k < H2; ++k) acc += x[k] * w[k];
    out[tid] = acc;
}

extern "C" void kernel_launch(void* const* d_in, const int* in_sizes, int n_in,
                              void* d_out, int out_size, void* d_ws, size_t ws_size,
                              hipStream_t stream) {
    const float* input_enc      = (const float*)d_in[0];
    const float* input_attW_enc = (const float*)d_in[1];
    const float* input_dec      = (const float*)d_in[2];
    const float* style_vec      = (const float*)d_in[3];
    const int*   lengths_enc    = (const int*)d_in[4];
    const float* pw1  = (const float*)d_in[5];
    const float* pb1  = (const float*)d_in[6];
    const float* pw2  = (const float*)d_in[7];
    const float* pb2  = (const float*)d_in[8];
    const float* wdec = (const float*)d_in[9];
    const float* bdec = (const float*)d_in[10];
    const float* ga_ih  = (const float*)d_in[11];
    const float* ga_bih = (const float*)d_in[13];
    const float* ga_bhh = (const float*)d_in[14];
    const float* wattn  = (const float*)d_in[15];
    const float* battn  = (const float*)d_in[16];
    const float* wsc    = (const float*)d_in[17];
    const float* bsc    = (const float*)d_in[18];
    const float* g1_ih  = (const float*)d_in[19];
    const float* g1_bih = (const float*)d_in[21];
    const float* g1_bhh = (const float*)d_in[22];
    const float* g2_ih  = (const float*)d_in[23];
    const float* g2_bih = (const float*)d_in[25];
    const float* g2_bhh = (const float*)d_in[26];
    const float* wout   = (const float*)d_in[27];
    const float* bout   = (const float*)d_in[28];
    float* out = (float*)d_out;

    // workspace layout (floats)
    float* ws = (float*)d_ws;
    float* num      = ws;                 // 32768  (zeroed)
    float* den      = ws + 32768;         // 64     (zeroed)
    float* t1       = ws + 32832;         // 32768
    float* pre      = ws + 65600;         // 16384
    float* out_att  = ws + 81984;         // 32768
    float* attW_dec = ws + 114752;        // 32768
    float* ew       = ws + 147520;        // 65536
    float* out_dec  = ws + 213056;        // 73728
    float* res1     = ws + 286784;        // 32768
    float* res2     = ws + 319552;        // 32768

    hipMemsetAsync(num, 0, (32768 + 64) * sizeof(float), stream);

    k_l1<<<128, 256, 0, stream>>>(input_dec, pw1, pb1, t1);
    k_l2<<<64, 256, 0, stream>>>(t1, pw2, pb2, pre);
    k_gruA<<<128, 256, 0, stream>>>(pre, style_vec, ga_ih, ga_bih, ga_bhh, out_att);
    k_attw<<<128, 256, 0, stream>>>(out_att, wdec, bdec, attW_dec);
    k_score<<<NB * TT / 4, 256, 0, stream>>>(input_attW_enc, attW_dec, wattn, battn,
                                             lengths_enc, ew, den);
    k_apply<<<dim3(16, NB), 256, 0, stream>>>(input_enc, ew, num);
    k_finalize<<<128, 256, 0, stream>>>(num, den, out_att, style_vec, out, out_dec);
    k_sc_h1<<<128, 256, 0, stream>>>(out_dec, wsc, bsc, g1_ih, g1_bih, g1_bhh, res1);
    k_h2<<<128, 256, 0, stream>>>(res1, g2_ih, g2_bih, g2_bhh, res2);
    k_out<<<40, 256, 0, stream>>>(res2, wout, bout, out);
}

// Round 2
// 411.475 us; speedup vs baseline: 2.9790x; 2.9790x over previous
//
#include <hip/hip_runtime.h>
#include <math.h>

#define NB  64
#define TT  1024
#define H2  512      // 2*H
#define HH  256      // H
#define SS  128      // style dim
#define OO  80
#define FIN_A 896    // 3H+S (ga_ih inner dim)
#define FIN_1 1152   // 4H+S (wsc / g1_ih inner dim)
#define CH  16       // t-chunks for fused attention (64 t per block, 16 per wave)

__device__ __forceinline__ float fast_sigmoid(float x) { return 1.0f / (1.0f + __expf(-x)); }
__device__ __forceinline__ float fast_tanh(float x) {
    float xc = fminf(fmaxf(x, -15.0f), 15.0f);
    float e = __expf(2.0f * xc);
    return (e - 1.0f) / (e + 1.0f);
}
__device__ __forceinline__ float wred(float p) {
    #pragma unroll
    for (int o = 32; o > 0; o >>= 1) p += __shfl_xor(p, o, 64);
    return p;
}

// t1 = relu(input_dec @ pw1.T + pb1)   (64,512)  K=80, tiny — thread per output
__global__ void k_l1(const float* __restrict__ xdec, const float* __restrict__ pw1,
                     const float* __restrict__ pb1, float* __restrict__ t1) {
    int tid = blockIdx.x * blockDim.x + threadIdx.x;
    int n = tid >> 9, i = tid & 511;
    float acc = pb1[i];
    const float* x = xdec + n * OO;
    const float* w = pw1 + i * OO;
    #pragma unroll 8
    for (int k = 0; k < OO; ++k) acc += x[k] * w[k];
    t1[tid] = fmaxf(acc, 0.0f);
}

// pre = relu(t1 @ pw2.T + pb2)   (64,256)  wave per output, K=512
__global__ void k_l2(const float* __restrict__ t1, const float* __restrict__ pw2,
                     const float* __restrict__ pb2, float* __restrict__ pre) {
    int gw = (blockIdx.x * blockDim.x + threadIdx.x) >> 6;   // n*256 + i
    int lane = threadIdx.x & 63;
    int n = gw >> 8, i = gw & 255;
    const float* x = t1 + n * H2;
    const float* w = pw2 + (size_t)i * H2;
    float p = 0.0f;
    #pragma unroll
    for (int m = 0; m < 8; ++m) { int k = lane + 64 * m; p += x[k] * w[k]; }
    p = wred(p);
    if (lane == 0) pre[gw] = fmaxf(p + pb2[i], 0.0f);
}

// out_att = GRU(x_att, h=0): x_att = [pre(256), zeros(512), sv(128)]; gh = b_hh only.
// wave per (n,j)
__global__ void k_gruA(const float* __restrict__ pre, const float* __restrict__ sv,
                       const float* __restrict__ ga_ih, const float* __restrict__ ga_bih,
                       const float* __restrict__ ga_bhh, float* __restrict__ out_att) {
    int gw = (blockIdx.x * blockDim.x + threadIdx.x) >> 6;   // n*512 + j
    int lane = threadIdx.x & 63;
    int n = gw >> 9, j = gw & 511;
    const float* wr = ga_ih + (size_t)j * FIN_A;
    const float* wz = ga_ih + (size_t)(H2 + j) * FIN_A;
    const float* wn = ga_ih + (size_t)(2 * H2 + j) * FIN_A;
    const float* xp = pre + n * HH;
    const float* xs = sv + n * SS;
    float pr = 0.0f, pz = 0.0f, pn = 0.0f;
    #pragma unroll
    for (int m = 0; m < 4; ++m) {
        int k = lane + 64 * m;
        float x = xp[k];
        pr += x * wr[k]; pz += x * wz[k]; pn += x * wn[k];
    }
    #pragma unroll
    for (int m = 0; m < 2; ++m) {
        int k = lane + 64 * m;
        float x = xs[k];
        pr += x * wr[768 + k]; pz += x * wz[768 + k]; pn += x * wn[768 + k];
    }
    pr = wred(pr); pz = wred(pz); pn = wred(pn);
    if (lane == 0) {
        float r = fast_sigmoid(pr + ga_bih[j] + ga_bhh[j]);
        float z = fast_sigmoid(pz + ga_bih[H2 + j] + ga_bhh[H2 + j]);
        float nn = fast_tanh(pn + ga_bih[2 * H2 + j] + r * ga_bhh[2 * H2 + j]);
        out_att[gw] = (1.0f - z) * nn;
    }
}

// attW_dec = out_att @ wdec.T + bdec   (64,512)  wave per output
__global__ void k_attw(const float* __restrict__ out_att, const float* __restrict__ wdec,
                       const float* __restrict__ bdec, float* __restrict__ attW_dec) {
    int gw = (blockIdx.x * blockDim.x + threadIdx.x) >> 6;   // n*512 + i
    int lane = threadIdx.x & 63;
    int n = gw >> 9, i = gw & 511;
    const float* x = out_att + n * H2;
    const float* w = wdec + (size_t)i * H2;
    float p = 0.0f;
    #pragma unroll
    for (int m = 0; m < 8; ++m) { int k = lane + 64 * m; p += x[k] * w[k]; }
    p = wred(p);
    if (lane == 0) attW_dec[gw] = p + bdec[i];
}

// Fused attention: per (n, t-chunk) block; accumulates unnormalized num & den.
// grid dim3(CH, NB), 256 threads. Wave handles 16 t's; lane owns d = lane*8..+7.
__global__ void k_attn(const float* __restrict__ enc, const float* __restrict__ attw_enc,
                       const float* __restrict__ attW_dec, const float* __restrict__ wattn,
                       const float* __restrict__ battn, const int* __restrict__ lengths,
                       float* __restrict__ num_part /*[CH][NB][512]*/,
                       float* __restrict__ den_part /*[CH][NB]*/) {
    int n = blockIdx.y;
    int wv = threadIdx.x >> 6, lane = threadIdx.x & 63;
    int tbase = blockIdx.x * (TT / CH) + wv * (TT / CH / 4);
    int d0 = lane * 8;
    const float4* dW = (const float4*)(attW_dec + n * H2 + d0);
    float4 dw0 = dW[0], dw1 = dW[1];
    const float4* aW = (const float4*)(wattn + d0);
    float4 w0 = aW[0], w1 = aW[1];
    float b = battn[0];
    int len = lengths[n];
    float4 acc0 = {0, 0, 0, 0}, acc1 = {0, 0, 0, 0};
    float denp = 0.0f;
    #pragma unroll 4
    for (int tt = 0; tt < TT / CH / 4; ++tt) {
        int t = tbase + tt;
        size_t rowoff = ((size_t)(n * TT + t)) * H2 + d0;
        const float4* e4 = (const float4*)(attw_enc + rowoff);
        float4 e0 = e4[0], e1 = e4[1];
        const float4* v4 = (const float4*)(enc + rowoff);
        float4 v0 = v4[0], v1 = v4[1];
        float p = fast_tanh(e0.x + dw0.x) * w0.x + fast_tanh(e0.y + dw0.y) * w0.y +
                  fast_tanh(e0.z + dw0.z) * w0.z + fast_tanh(e0.w + dw0.w) * w0.w +
                  fast_tanh(e1.x + dw1.x) * w1.x + fast_tanh(e1.y + dw1.y) * w1.y +
                  fast_tanh(e1.z + dw1.z) * w1.z + fast_tanh(e1.w + dw1.w) * w1.w;
        p = wred(p);
        float wt = (t < len) ? __expf(p + b) : 0.0f;
        acc0.x += wt * v0.x; acc0.y += wt * v0.y; acc0.z += wt * v0.z; acc0.w += wt * v0.w;
        acc1.x += wt * v1.x; acc1.y += wt * v1.y; acc1.z += wt * v1.z; acc1.w += wt * v1.w;
        denp += wt;
    }
    __shared__ float s[4 * 512];
    __shared__ float sd[4];
    float4* srow = (float4*)(s + wv * 512 + d0);
    srow[0] = acc0; srow[1] = acc1;
    if (lane == 0) sd[wv] = denp;
    __syncthreads();
    int d = threadIdx.x;
    float r0 = s[d] + s[512 + d] + s[1024 + d] + s[1536 + d];
    float r1 = s[256 + d] + s[512 + 256 + d] + s[1024 + 256 + d] + s[1536 + 256 + d];
    float* np = num_part + ((size_t)blockIdx.x * NB + n) * H2;
    np[d] = r0;
    np[256 + d] = r1;
    if (threadIdx.x == 0) den_part[blockIdx.x * NB + n] = sd[0] + sd[1] + sd[2] + sd[3];
}

// Reduce partials -> attn_applied; write second output chunk and out_dec = [attn, out_att, sv]
__global__ void k_attn_reduce(const float* __restrict__ num_part, const float* __restrict__ den_part,
                              const float* __restrict__ out_att, const float* __restrict__ sv,
                              float* __restrict__ out, float* __restrict__ out_dec) {
    int tid = blockIdx.x * blockDim.x + threadIdx.x;   // n*512 + d
    int n = tid >> 9, d = tid & 511;
    float s = 0.0f;
    #pragma unroll
    for (int c = 0; c < CH; ++c) s += num_part[((size_t)c * NB + n) * H2 + d];
    float den = 0.0f;
    #pragma unroll
    for (int c = 0; c < CH; ++c) den += den_part[c * NB + n];
    float a = s / fmaxf(den, 1e-12f);
    out[NB * 160 + tid] = a;                // output 1: attn_applied
    float* od = out_dec + (size_t)n * FIN_1;
    od[d] = a;
    od[H2 + d] = out_att[tid];
    if (d < SS) od[2 * H2 + d] = sv[n * SS + d];
}

// residual1 = out_dec @ wsc.T + bsc + GRU1(out_dec, 0)   wave per (n,j), K=1152
__global__ void k_sc_h1(const float* __restrict__ out_dec, const float* __restrict__ wsc,
                        const float* __restrict__ bsc, const float* __restrict__ g1_ih,
                        const float* __restrict__ g1_bih, const float* __restrict__ g1_bhh,
                        float* __restrict__ res1) {
    int gw = (blockIdx.x * blockDim.x + threadIdx.x) >> 6;   // n*512 + j
    int lane = threadIdx.x & 63;
    int n = gw >> 9, j = gw & 511;
    const float* ws_ = wsc + (size_t)j * FIN_1;
    const float* wr = g1_ih + (size_t)j * FIN_1;
    const float* wz = g1_ih + (size_t)(H2 + j) * FIN_1;
    const float* wn = g1_ih + (size_t)(2 * H2 + j) * FIN_1;
    const float* x = out_dec + (size_t)n * FIN_1;
    float ps = 0.0f, pr = 0.0f, pz = 0.0f, pn = 0.0f;
    #pragma unroll 6
    for (int m = 0; m < 18; ++m) {
        int k = lane + 64 * m;
        float xv = x[k];
        ps += xv * ws_[k]; pr += xv * wr[k]; pz += xv * wz[k]; pn += xv * wn[k];
    }
    ps = wred(ps); pr = wred(pr); pz = wred(pz); pn = wred(pn);
    if (lane == 0) {
        float r = fast_sigmoid(pr + g1_bih[j] + g1_bhh[j]);
        float z = fast_sigmoid(pz + g1_bih[H2 + j] + g1_bhh[H2 + j]);
        float nn = fast_tanh(pn + g1_bih[2 * H2 + j] + r * g1_bhh[2 * H2 + j]);
        res1[gw] = ps + bsc[j] + (1.0f - z) * nn;
    }
}

// residual2 = residual1 + GRU2(residual1, 0)   wave per (n,j), K=512
__global__ void k_h2(const float* __restrict__ res1, const float* __restrict__ g2_ih,
                     const float* __restrict__ g2_bih, const float* __restrict__ g2_bhh,
                     float* __restrict__ res2) {
    int gw = (blockIdx.x * blockDim.x + threadIdx.x) >> 6;   // n*512 + j
    int lane = threadIdx.x & 63;
    int n = gw >> 9, j = gw & 511;
    const float* wr = g2_ih + (size_t)j * H2;
    const float* wz = g2_ih + (size_t)(H2 + j) * H2;
    const float* wn = g2_ih + (size_t)(2 * H2 + j) * H2;
    const float* x = res1 + n * H2;
    float pr = 0.0f, pz = 0.0f, pn = 0.0f;
    #pragma unroll
    for (int m = 0; m < 8; ++m) {
        int k = lane + 64 * m;
        float xv = x[k];
        pr += xv * wr[k]; pz += xv * wz[k]; pn += xv * wn[k];
    }
    pr = wred(pr); pz = wred(pz); pn = wred(pn);
    if (lane == 0) {
        float r = fast_sigmoid(pr + g2_bih[j] + g2_bhh[j]);
        float z = fast_sigmoid(pz + g2_bih[H2 + j] + g2_bhh[H2 + j]);
        float nn = fast_tanh(pn + g2_bih[2 * H2 + j] + r * g2_bhh[2 * H2 + j]);
        res2[gw] = res1[gw] + (1.0f - z) * nn;
    }
}

// output = res2 @ wout.T + bout  -> out[0 .. 10240)   wave per (n,i), K=512
__global__ void k_out(const float* __restrict__ res2, const float* __restrict__ wout,
                      const float* __restrict__ bout, float* __restrict__ out) {
    int gw = (blockIdx.x * blockDim.x + threadIdx.x) >> 6;   // n*160 + i
    int lane = threadIdx.x & 63;
    int n = gw / 160, i = gw % 160;
    const float* x = res2 + n * H2;
    const float* w = wout + (size_t)i * H2;
    float p = 0.0f;
    #pragma unroll
    for (int m = 0; m < 8; ++m) { int k = lane + 64 * m; p += x[k] * w[k]; }
    p = wred(p);
    if (lane == 0) out[gw] = p + bout[i];
}

extern "C" void kernel_launch(void* const* d_in, const int* in_sizes, int n_in,
                              void* d_out, int out_size, void* d_ws, size_t ws_size,
                              hipStream_t stream) {
    const float* input_enc      = (const float*)d_in[0];
    const float* input_attW_enc = (const float*)d_in[1];
    const float* input_dec      = (const float*)d_in[2];
    const float* style_vec      = (const float*)d_in[3];
    const int*   lengths_enc    = (const int*)d_in[4];
    const float* pw1  = (const float*)d_in[5];
    const float* pb1  = (const float*)d_in[6];
    const float* pw2  = (const float*)d_in[7];
    const float* pb2  = (const float*)d_in[8];
    const float* wdec = (const float*)d_in[9];
    const float* bdec = (const float*)d_in[10];
    const float* ga_ih  = (const float*)d_in[11];
    const float* ga_bih = (const float*)d_in[13];
    const float* ga_bhh = (const float*)d_in[14];
    const float* wattn  = (const float*)d_in[15];
    const float* battn  = (const float*)d_in[16];
    const float* wsc    = (const float*)d_in[17];
    const float* bsc    = (const float*)d_in[18];
    const float* g1_ih  = (const float*)d_in[19];
    const float* g1_bih = (const float*)d_in[21];
    const float* g1_bhh = (const float*)d_in[22];
    const float* g2_ih  = (const float*)d_in[23];
    const float* g2_bih = (const float*)d_in[25];
    const float* g2_bhh = (const float*)d_in[26];
    const float* wout   = (const float*)d_in[27];
    const float* bout   = (const float*)d_in[28];
    float* out = (float*)d_out;

    // workspace layout (floats) — all arrays fully written before read; no zeroing needed
    float* ws = (float*)d_ws;
    float* num_part = ws;                        // CH*64*512 = 524288
    float* den_part = ws + 524288;               // CH*64    = 1024
    float* t1       = ws + 525312;               // 32768
    float* pre      = ws + 558080;               // 16384
    float* out_att  = ws + 574464;               // 32768
    float* attW_dec = ws + 607232;               // 32768
    float* out_dec  = ws + 640000;               // 73728
    float* res1     = ws + 713728;               // 32768
    float* res2     = ws + 746496;               // 32768
    // total 779264 floats ≈ 3.0 MB

    k_l1<<<128, 256, 0, stream>>>(input_dec, pw1, pb1, t1);
    k_l2<<<4096, 256, 0, stream>>>(t1, pw2, pb2, pre);
    k_gruA<<<8192, 256, 0, stream>>>(pre, style_vec, ga_ih, ga_bih, ga_bhh, out_att);
    k_attw<<<8192, 256, 0, stream>>>(out_att, wdec, bdec, attW_dec);
    k_attn<<<dim3(CH, NB), 256, 0, stream>>>(input_enc, input_attW_enc, attW_dec,
                                             wattn, battn, lengths_enc, num_part, den_part);
    k_attn_reduce<<<128, 256, 0, stream>>>(num_part, den_part, out_att, style_vec, out, out_dec);
    k_sc_h1<<<8192, 256, 0, stream>>>(out_dec, wsc, bsc, g1_ih, g1_bih, g1_bhh, res1);
    k_h2<<<8192, 256, 0, stream>>>(res1, g2_ih, g2_bih, g2_bhh, res2);
    k_out<<<2560, 256, 0, stream>>>(res2, wout, bout, out);
}